// Round 10
// baseline (482.692 us; speedup 1.0000x reference)
//
#include <hip/hip_runtime.h>

#define TPB 256  // 4 waves; block = 64 rows; wave w owns q-quarter w

typedef _Float16 f16x8 __attribute__((ext_vector_type(8)));
typedef __fp16 h16x2 __attribute__((ext_vector_type(2)));  // cvt_pkrtz native type
typedef float f32x4 __attribute__((ext_vector_type(4)));

// fp16 weight tiles (16x16x32 B-fragment order), tile(n-1, s, t) of 512 f16:
static constexpr int WT_L0 = 0;        // 8n*2s*8t*512 = 65536
static constexpr int WT_L1 = 65536;    // 8n*4s*8t*512 = 131072 each
static constexpr int WT_L2 = 196608;
static constexpr int WT_L3 = 327680;
static constexpr int WT_END = 458752;          // f16 elements per plane (hi, lo)
static constexpr int F32_BASE = WT_END;        // float offset into ws (2 f16 planes)
static constexpr int MST = 132;                // shared mT row stride (floats)

// ---------- helpers ----------
__device__ __forceinline__ float fast_tanh2(float x) {  // 2*tanh(x)
  float e = __expf(2.0f * x);
  return fmaf(-4.0f, __builtin_amdgcn_rcpf(e + 1.0f), 2.0f);
}
__device__ __forceinline__ float gelu_exact(float v) {
  return 0.5f * v * (1.0f + erff(v * 0.70710678f));
}

// ---------- fusion kernels (verified R8 layout) ----------
// within-tile e = lane*8 + j: q = lane&15 (bits 3..6), g = lane>>4 (bits 7..8)
// p = s*32 + g*8 + j ; qg = t*16 + q ; coef n = n1+1
__global__ void fuse_w_f16(const float* __restrict__ W, const float* __restrict__ tW,
                           _Float16* __restrict__ out_hi, _Float16* __restrict__ out_lo,
                           int P, int total, int sbits) {
  int i = blockIdx.x * 256 + threadIdx.x;
  if (i >= total) return;
  int j = i & 7, q = (i >> 3) & 15, g = (i >> 7) & 3, t = (i >> 9) & 7;
  int s = (i >> 12) & ((1 << sbits) - 1);
  int n1 = i >> (12 + sbits);  // n-1 in 0..7
  int p = s * 32 + g * 8 + j;
  int qg = t * 16 + q;
  float v = tW[(qg * P + p) * 9 + (n1 + 1)] * W[qg * P + p];
  _Float16 hi = (_Float16)v;
  out_hi[i] = hi;
  out_lo[i] = (_Float16)(v - (float)hi);
}
// bias[q] = sum_p tW[q,p,0]*W[q,p]   (the n=0 / T0=1 term)
__global__ void fuse_bias(const float* __restrict__ W, const float* __restrict__ tW,
                          float* __restrict__ bias, int P, int Q) {
  int q = blockIdx.x * 64 + threadIdx.x;
  if (q >= Q) return;
  float s = 0.0f;
  for (int p = 0; p < P; ++p) s += tW[(q * P + p) * 9] * W[q * P + p];
  bias[q] = s;
}
// w4[p*9+n] = tW4[p*9+n] * W4[p]
__global__ void fuse_w4(const float* __restrict__ W, const float* __restrict__ tW,
                        float* __restrict__ out) {
  int i = blockIdx.x * 128 + threadIdx.x;
  if (i >= 1152) return;
  out[i] = tW[i] * W[i / 9];
}

// ---------- per-layer MFMA: 64 rows (4 row-tiles) x 32 q (2 q-tiles) ----------
// mT[r*MST + p] shared fp32; acc[rt][qt] C: row=rt*16+(l>>4)*4+j, col=wq*32+qt*16+(l&15)
template <int S, bool RES>
__device__ __forceinline__ void layer_mfma(const float* __restrict__ mT,
                                           const _Float16* __restrict__ wt_hi,
                                           const _Float16* __restrict__ wt_lo,
                                           const float* __restrict__ biasL,
                                           f32x4 (&acc)[4][2], int l, int wq) {
  const int c15 = l & 15, g = l >> 4;
#pragma unroll
  for (int qt = 0; qt < 2; ++qt) {
    float bv = biasL[wq * 32 + qt * 16 + c15];
#pragma unroll
    for (int rt = 0; rt < 4; ++rt)
#pragma unroll
      for (int j = 0; j < 4; ++j) {
        if (RES) acc[rt][qt][j] += bv; else acc[rt][qt][j] = bv;
      }
  }
  const _Float16* slot_hi = wt_hi + wq * 1024 + l * 8;  // tiles t = 2wq, 2wq+1
  const _Float16* slot_lo = wt_lo + wq * 1024 + l * 8;
  float mv[4][8], up[4][8], uc[4][8];
  f16x8 bh0[2], bl0[2], bh1[2], bl1[2];

#define LB(dh, dl, ks)                                                        \
  {                                                                           \
    int s_ = (ks) >> 3, n_ = (ks) & 7;                                        \
    size_t off_ = (size_t)(n_ * S + s_) * 4096;                               \
    _Pragma("unroll") for (int qt = 0; qt < 2; ++qt) {                        \
      dh[qt] = *(const f16x8*)(slot_hi + off_ + qt * 512);                    \
      dl[qt] = *(const f16x8*)(slot_lo + off_ + qt * 512);                    \
    }                                                                         \
  }

#define AREAD(s_)                                                             \
  {                                                                           \
    _Pragma("unroll") for (int rt = 0; rt < 4; ++rt) {                        \
      const f32x4* mp_ =                                                      \
          (const f32x4*)(mT + (rt * 16 + c15) * MST + (s_) * 32 + g * 8);     \
      f32x4 a_ = mp_[0], b_ = mp_[1];                                         \
      _Pragma("unroll") for (int ii = 0; ii < 4; ++ii) {                      \
        mv[rt][ii] = a_[ii]; mv[rt][4 + ii] = b_[ii];                         \
      }                                                                       \
      _Pragma("unroll") for (int ii = 0; ii < 8; ++ii) {                      \
        up[rt][ii] = 1.0f; uc[rt][ii] = mv[rt][ii];                           \
      }                                                                       \
    }                                                                         \
  }

#define STEP(bh, bl)                                                          \
  {                                                                           \
    f16x8 afh[4], afl[4];                                                     \
    _Pragma("unroll") for (int rt = 0; rt < 4; ++rt) {                        \
      union U8 { h16x2 h2[4]; f16x8 v; } uh_, ul_;                            \
      _Pragma("unroll") for (int ii = 0; ii < 4; ++ii) {                      \
        float v0 = uc[rt][2 * ii], v1 = uc[rt][2 * ii + 1];                   \
        h16x2 h_ = __builtin_amdgcn_cvt_pkrtz(v0, v1);                        \
        uh_.h2[ii] = h_;                                                      \
        ul_.h2[ii] = __builtin_amdgcn_cvt_pkrtz(v0 - (float)h_[0],            \
                                                v1 - (float)h_[1]);           \
      }                                                                       \
      afh[rt] = uh_.v; afl[rt] = ul_.v;                                       \
    }                                                                         \
    _Pragma("unroll") for (int rt = 0; rt < 4; ++rt)                          \
      _Pragma("unroll") for (int ii = 0; ii < 8; ++ii) {                      \
        float u_ = fmaf(mv[rt][ii], uc[rt][ii], -up[rt][ii]);                 \
        up[rt][ii] = uc[rt][ii]; uc[rt][ii] = u_;                             \
      }                                                                       \
    _Pragma("unroll") for (int qt = 0; qt < 2; ++qt)                          \
      _Pragma("unroll") for (int rt = 0; rt < 4; ++rt)                        \
        acc[rt][qt] = __builtin_amdgcn_mfma_f32_16x16x32_f16(                 \
            afh[rt], bh[qt], acc[rt][qt], 0, 0, 0);                           \
    _Pragma("unroll") for (int qt = 0; qt < 2; ++qt)                          \
      _Pragma("unroll") for (int rt = 0; rt < 4; ++rt)                        \
        acc[rt][qt] = __builtin_amdgcn_mfma_f32_16x16x32_f16(                 \
            afl[rt], bh[qt], acc[rt][qt], 0, 0, 0);                           \
    _Pragma("unroll") for (int qt = 0; qt < 2; ++qt)                          \
      _Pragma("unroll") for (int rt = 0; rt < 4; ++rt)                        \
        acc[rt][qt] = __builtin_amdgcn_mfma_f32_16x16x32_f16(                 \
            afh[rt], bl[qt], acc[rt][qt], 0, 0, 0);                           \
  }

  LB(bh0, bl0, 0);
#pragma unroll 1
  for (int i = 0; i < 4 * S; ++i) {
    int ks = 2 * i;
    if ((ks & 7) == 0) AREAD(ks >> 3);
    LB(bh1, bl1, ks + 1);
    STEP(bh0, bl0);
    if (ks + 2 < 8 * S) LB(bh0, bl0, ks + 2);
    STEP(bh1, bl1);
  }
#undef LB
#undef AREAD
#undef STEP
}

// write m = 2tanh(acc) into shared mT (wave's q-quarter = next layer's p)
__device__ __forceinline__ void write_m(float* __restrict__ mT,
                                        const f32x4 (&acc)[4][2], int l, int wq) {
  const int c15 = l & 15, g = l >> 4;
#pragma unroll
  for (int rt = 0; rt < 4; ++rt)
#pragma unroll
    for (int qt = 0; qt < 2; ++qt)
#pragma unroll
      for (int j = 0; j < 4; ++j) {
        int row = rt * 16 + g * 4 + j;
        int col = wq * 32 + qt * 16 + c15;
        mT[row * MST + col] = fast_tanh2(acc[rt][qt][j]);
      }
}

// ---------- main kernel ----------
__global__ void __launch_bounds__(TPB, 2)
kan_mfma(const float* __restrict__ x, const float* __restrict__ Bm,
         const _Float16* __restrict__ wt_hi, const _Float16* __restrict__ wt_lo,
         const float* __restrict__ bias, const float* __restrict__ w4,
         float* __restrict__ out) {
  __shared__ float mT[64 * MST];  // 33.8 KB shared residual-activation tile
  int tid = threadIdx.x;
  int l = tid & 63;
  int wq = tid >> 6;
  int row0 = blockIdx.x * 64;

  // ---- Fourier features -> mT rows (thread: row=l, features wq*8..wq*8+7) ----
  {
    const float4* xp = (const float4*)(x + (size_t)(row0 + l) * 8);
    float4 a = xp[0], c4 = xp[1];
    float xv[8] = {a.x, a.y, a.z, a.w, c4.x, c4.y, c4.z, c4.w};
#pragma unroll
    for (int jj = 0; jj < 8; ++jj) {
      int j = wq * 8 + jj;
      float pr = 0.0f;
#pragma unroll
      for (int k = 0; k < 8; ++k) pr = fmaf(xv[k], Bm[k * 32 + j], pr);
      float ang = 6.2831853071795864f * pr;
      float sv, cv;
      sincosf(ang, &sv, &cv);
      mT[l * MST + j] = fast_tanh2(sv);
      mT[l * MST + 32 + j] = fast_tanh2(cv);
    }
  }
  __syncthreads();

  f32x4 acc[4][2];
  layer_mfma<2, false>(mT, wt_hi + WT_L0, wt_lo + WT_L0, bias + 0, acc, l, wq);
  __syncthreads();
  write_m(mT, acc, l, wq);
  __syncthreads();
  layer_mfma<4, true>(mT, wt_hi + WT_L1, wt_lo + WT_L1, bias + 128, acc, l, wq);
  __syncthreads();
  write_m(mT, acc, l, wq);
  __syncthreads();
  layer_mfma<4, true>(mT, wt_hi + WT_L2, wt_lo + WT_L2, bias + 256, acc, l, wq);
  __syncthreads();
  write_m(mT, acc, l, wq);
  __syncthreads();
  layer_mfma<4, true>(mT, wt_hi + WT_L3, wt_lo + WT_L3, bias + 384, acc, l, wq);
  __syncthreads();
  write_m(mT, acc, l, wq);
  __syncthreads();

  // ---- L4: 128 -> 1 (wave wq handles rows wq*16..+15; lanes split p in 4) ----
  {
    int r16 = l & 15, pq = l >> 4;
    int r = wq * 16 + r16;
    const float* w4h = w4 + pq * 32 * 9;
    float part = 0.0f;
#pragma unroll 4
    for (int pp = 0; pp < 32; ++pp) {
      float mm = mT[r * MST + pq * 32 + pp];
      const float* wp = w4h + pp * 9;
      part += wp[0];
      part = fmaf(mm, wp[1], part);
      float u2 = 1.0f, u1 = mm;
#pragma unroll
      for (int n = 2; n < 9; ++n) {
        float u = fmaf(mm, u1, -u2);
        u2 = u1;
        u1 = u;
        part = fmaf(u, wp[n], part);
      }
    }
    part += __shfl_xor(part, 16);
    part += __shfl_xor(part, 32);
    if (l < 16) {
      float v = part;
      // cheby-gelu, degree 5, T1 = tanh(v)
      float t = 0.5f * fast_tanh2(v);
      float m2 = t + t;
      float tm2 = 1.0f, tm1 = t;
      float y = gelu_exact(1.0f) + gelu_exact(t);
#pragma unroll
      for (int n = 2; n <= 5; ++n) {
        float tn = fmaf(m2, tm1, -tm2);
        tm2 = tm1;
        tm1 = tn;
        y += gelu_exact(tn);
      }
      out[row0 + r] = y;
    }
  }
}

extern "C" void kernel_launch(void* const* d_in, const int* in_sizes, int n_in,
                              void* d_out, int out_size, void* d_ws, size_t ws_size,
                              hipStream_t stream) {
  const float* x   = (const float*)d_in[0];
  const float* Bm  = (const float*)d_in[1];
  const float* W0  = (const float*)d_in[2];
  const float* tW0 = (const float*)d_in[3];
  const float* W1  = (const float*)d_in[4];
  const float* tW1 = (const float*)d_in[5];
  const float* W2  = (const float*)d_in[6];
  const float* tW2 = (const float*)d_in[7];
  const float* W3  = (const float*)d_in[8];
  const float* tW3 = (const float*)d_in[9];
  const float* W4  = (const float*)d_in[10];
  const float* tW4 = (const float*)d_in[11];

  _Float16* wt_hi = (_Float16*)d_ws;
  _Float16* wt_lo = wt_hi + WT_END;
  float* fws = (float*)d_ws + F32_BASE;
  float* bias = fws;        // 4*128 floats
  float* w4 = fws + 512;    // 1152 floats

  fuse_w_f16<<<65536 / 256, 256, 0, stream>>>(W0, tW0, wt_hi + WT_L0, wt_lo + WT_L0, 64, 65536, 1);
  fuse_w_f16<<<131072 / 256, 256, 0, stream>>>(W1, tW1, wt_hi + WT_L1, wt_lo + WT_L1, 128, 131072, 2);
  fuse_w_f16<<<131072 / 256, 256, 0, stream>>>(W2, tW2, wt_hi + WT_L2, wt_lo + WT_L2, 128, 131072, 2);
  fuse_w_f16<<<131072 / 256, 256, 0, stream>>>(W3, tW3, wt_hi + WT_L3, wt_lo + WT_L3, 128, 131072, 2);
  fuse_bias<<<2, 64, 0, stream>>>(W0, tW0, bias + 0, 64, 128);
  fuse_bias<<<2, 64, 0, stream>>>(W1, tW1, bias + 128, 128, 128);
  fuse_bias<<<2, 64, 0, stream>>>(W2, tW2, bias + 256, 128, 128);
  fuse_bias<<<2, 64, 0, stream>>>(W3, tW3, bias + 384, 128, 128);
  fuse_w4<<<9, 128, 0, stream>>>(W4, tW4, w4);

  kan_mfma<<<131072 / 64, TPB, 0, stream>>>(x, Bm, wt_hi, wt_lo, bias, w4, (float*)d_out);
}

// Round 11
// 411.487 us; speedup vs baseline: 1.1730x; 1.1730x over previous
//
#include <hip/hip_runtime.h>

#define TPB 256  // 4 waves; block = 64 rows; wave wq owns q-quarter; A staged cooperatively

typedef _Float16 f16x8 __attribute__((ext_vector_type(8)));
typedef __fp16 h16x2 __attribute__((ext_vector_type(2)));  // cvt_pkrtz native type
typedef float f32x4 __attribute__((ext_vector_type(4)));

// fp16 weight tiles (16x16x32 B-fragment order), tile(n-1, s, t) of 512 f16:
static constexpr int WT_L0 = 0;        // 8n*2s*8t*512 = 65536
static constexpr int WT_L1 = 65536;    // 8n*4s*8t*512 = 131072 each
static constexpr int WT_L2 = 196608;
static constexpr int WT_L3 = 327680;
static constexpr int WT_END = 458752;          // f16 elements per plane (hi, lo)
static constexpr int F32_BASE = WT_END;        // float offset into ws (2 f16 planes)
static constexpr int MST = 132;                // mT row stride (floats)

// ---------- helpers ----------
__device__ __forceinline__ float fast_tanh2(float x) {  // 2*tanh(x)
  float e = __expf(2.0f * x);
  return fmaf(-4.0f, __builtin_amdgcn_rcpf(e + 1.0f), 2.0f);
}
__device__ __forceinline__ float gelu_exact(float v) {
  return 0.5f * v * (1.0f + erff(v * 0.70710678f));
}

// ---------- fusion kernels (verified R8 layout) ----------
// within-tile e = lane*8 + j: q = lane&15 (bits 3..6), g = lane>>4 (bits 7..8)
// p = s*32 + g*8 + j ; qg = t*16 + q ; coef n = n1+1
__global__ void fuse_w_f16(const float* __restrict__ W, const float* __restrict__ tW,
                           _Float16* __restrict__ out_hi, _Float16* __restrict__ out_lo,
                           int P, int total, int sbits) {
  int i = blockIdx.x * 256 + threadIdx.x;
  if (i >= total) return;
  int j = i & 7, q = (i >> 3) & 15, g = (i >> 7) & 3, t = (i >> 9) & 7;
  int s = (i >> 12) & ((1 << sbits) - 1);
  int n1 = i >> (12 + sbits);  // n-1 in 0..7
  int p = s * 32 + g * 8 + j;
  int qg = t * 16 + q;
  float v = tW[(qg * P + p) * 9 + (n1 + 1)] * W[qg * P + p];
  _Float16 hi = (_Float16)v;
  out_hi[i] = hi;
  out_lo[i] = (_Float16)(v - (float)hi);
}
__global__ void fuse_bias(const float* __restrict__ W, const float* __restrict__ tW,
                          float* __restrict__ bias, int P, int Q) {
  int q = blockIdx.x * 64 + threadIdx.x;
  if (q >= Q) return;
  float s = 0.0f;
  for (int p = 0; p < P; ++p) s += tW[(q * P + p) * 9] * W[q * P + p];
  bias[q] = s;
}
__global__ void fuse_w4(const float* __restrict__ W, const float* __restrict__ tW,
                        float* __restrict__ out) {
  int i = blockIdx.x * 128 + threadIdx.x;
  if (i >= 1152) return;
  out[i] = tW[i] * W[i / 9];
}

// ---------- cooperative layer ----------
// Chunk k = s*8 + (n-1). STAGE: thread (wrow,wg) advances T_n for its 8 p,
// packs hi/lo, writes lane-ordered A-frags. CONSUME: 8 ds_read + 4 B loads + 24 MFMA.
#define STAGE(k)                                                               \
  {                                                                            \
    int s_ = (k) >> 3, n1_ = (k) & 7, bf_ = (k) & 1;                           \
    if (n1_ == 0) {                                                            \
      const f32x4* mp_ = (const f32x4*)(mT + wrow * MST + s_ * 32 + wg * 8);   \
      f32x4 a_ = mp_[0], b_ = mp_[1];                                          \
      _Pragma("unroll") for (int i = 0; i < 4; ++i) {                          \
        mv[i] = a_[i]; mv[4 + i] = b_[i];                                      \
      }                                                                        \
      _Pragma("unroll") for (int i = 0; i < 8; ++i) {                          \
        up[i] = 1.0f; uc[i] = mv[i];                                           \
      }                                                                        \
    } else {                                                                   \
      _Pragma("unroll") for (int i = 0; i < 8; ++i) {                          \
        float u_ = fmaf(mv[i], uc[i], -up[i]);                                 \
        up[i] = uc[i]; uc[i] = u_;                                             \
      }                                                                        \
    }                                                                          \
    union UU { h16x2 h2[4]; f16x8 v; } uh_, ul_;                               \
    _Pragma("unroll") for (int ii = 0; ii < 4; ++ii) {                         \
      float v0 = uc[2 * ii], v1 = uc[2 * ii + 1];                              \
      h16x2 h_ = __builtin_amdgcn_cvt_pkrtz(v0, v1);                           \
      uh_.h2[ii] = h_;                                                         \
      ul_.h2[ii] =                                                             \
          __builtin_amdgcn_cvt_pkrtz(v0 - (float)h_[0], v1 - (float)h_[1]);    \
    }                                                                          \
    *(f16x8*)&abuf[bf_][wrt][0][wslot * 8] = uh_.v;                            \
    *(f16x8*)&abuf[bf_][wrt][1][wslot * 8] = ul_.v;                            \
  }

#define CONSUME(k)                                                             \
  {                                                                            \
    int s_ = (k) >> 3, n1_ = (k) & 7, bf_ = (k) & 1;                           \
    size_t toff_ = (size_t)(n1_ * S + s_) * 4096 + wq * 1024 + l * 8;          \
    f16x8 bh_[2], bl_[2];                                                      \
    bh_[0] = *(const f16x8*)(wt_hi + toff_);                                   \
    bh_[1] = *(const f16x8*)(wt_hi + toff_ + 512);                             \
    bl_[0] = *(const f16x8*)(wt_lo + toff_);                                   \
    bl_[1] = *(const f16x8*)(wt_lo + toff_ + 512);                             \
    f16x8 ah_[4], al_[4];                                                      \
    _Pragma("unroll") for (int rt = 0; rt < 4; ++rt) {                         \
      ah_[rt] = *(const f16x8*)&abuf[bf_][rt][0][l * 8];                       \
      al_[rt] = *(const f16x8*)&abuf[bf_][rt][1][l * 8];                       \
    }                                                                          \
    _Pragma("unroll") for (int qt = 0; qt < 2; ++qt)                           \
      _Pragma("unroll") for (int rt = 0; rt < 4; ++rt)                         \
          acc[rt][qt] = __builtin_amdgcn_mfma_f32_16x16x32_f16(                \
              ah_[rt], bh_[qt], acc[rt][qt], 0, 0, 0);                         \
    _Pragma("unroll") for (int qt = 0; qt < 2; ++qt)                           \
      _Pragma("unroll") for (int rt = 0; rt < 4; ++rt)                         \
          acc[rt][qt] = __builtin_amdgcn_mfma_f32_16x16x32_f16(                \
              al_[rt], bh_[qt], acc[rt][qt], 0, 0, 0);                         \
    _Pragma("unroll") for (int qt = 0; qt < 2; ++qt)                           \
      _Pragma("unroll") for (int rt = 0; rt < 4; ++rt)                         \
          acc[rt][qt] = __builtin_amdgcn_mfma_f32_16x16x32_f16(                \
              ah_[rt], bl_[qt], acc[rt][qt], 0, 0, 0);                         \
  }

template <int S, bool RES>
__device__ __forceinline__ void layer_coop(float* __restrict__ mT,
                                           _Float16 (*abuf)[4][2][512],
                                           const _Float16* __restrict__ wt_hi,
                                           const _Float16* __restrict__ wt_lo,
                                           const float* __restrict__ biasL,
                                           f32x4 (&acc)[4][2], int l, int wq,
                                           int wrow, int wg, int wrt, int wslot) {
  const int c15 = l & 15;
#pragma unroll
  for (int qt = 0; qt < 2; ++qt) {
    float bv = biasL[wq * 32 + qt * 16 + c15];
#pragma unroll
    for (int rt = 0; rt < 4; ++rt)
#pragma unroll
      for (int j = 0; j < 4; ++j) {
        if (RES) acc[rt][qt][j] += bv; else acc[rt][qt][j] = bv;
      }
  }
  float mv[8], up[8], uc[8];
  constexpr int NCH = 8 * S;
  STAGE(0)
  __syncthreads();
#pragma unroll 1
  for (int k = 0; k < NCH; ++k) {
    if (k + 1 < NCH) STAGE(k + 1)
    CONSUME(k)
    __syncthreads();
  }
}

// write m = 2tanh(acc) into mT; acc C-layout: row=rt*16+(l>>4)*4+j, col=wq*32+qt*16+(l&15)
__device__ __forceinline__ void write_m(float* __restrict__ mT,
                                        const f32x4 (&acc)[4][2], int l, int wq) {
  const int c15 = l & 15, g = l >> 4;
#pragma unroll
  for (int rt = 0; rt < 4; ++rt)
#pragma unroll
    for (int qt = 0; qt < 2; ++qt)
#pragma unroll
      for (int j = 0; j < 4; ++j) {
        int row = rt * 16 + g * 4 + j;
        int col = wq * 32 + qt * 16 + c15;
        mT[row * MST + col] = fast_tanh2(acc[rt][qt][j]);
      }
}

// ---------- main kernel ----------
__global__ void __launch_bounds__(TPB, 3)
kan_mfma(const float* __restrict__ x, const float* __restrict__ Bm,
         const _Float16* __restrict__ wt_hi, const _Float16* __restrict__ wt_lo,
         const float* __restrict__ bias, const float* __restrict__ w4,
         float* __restrict__ out) {
  __shared__ float mT[64 * MST];                          // 33.8 KB
  __shared__ __align__(16) _Float16 abuf[2][4][2][512];   // 16 KB, dbuf A-frags
  int tid = threadIdx.x;
  int l = tid & 63;
  int wq = tid >> 6;
  int wrow = tid >> 2;          // writer row 0..63
  int wg = tid & 3;             // writer k-group 0..3
  int wrt = wrow >> 4;
  int wslot = wg * 16 + (wrow & 15);
  int row0 = blockIdx.x * 64;

  // ---- Fourier features -> mT (thread: row=l, features wq*8..wq*8+7) ----
  {
    const float4* xp = (const float4*)(x + (size_t)(row0 + l) * 8);
    float4 a = xp[0], c4 = xp[1];
    float xv[8] = {a.x, a.y, a.z, a.w, c4.x, c4.y, c4.z, c4.w};
#pragma unroll
    for (int jj = 0; jj < 8; ++jj) {
      int j = wq * 8 + jj;
      float pr = 0.0f;
#pragma unroll
      for (int k = 0; k < 8; ++k) pr = fmaf(xv[k], Bm[k * 32 + j], pr);
      float ang = 6.2831853071795864f * pr;
      float sv, cv;
      sincosf(ang, &sv, &cv);
      mT[l * MST + j] = fast_tanh2(sv);
      mT[l * MST + 32 + j] = fast_tanh2(cv);
    }
  }
  __syncthreads();

  f32x4 acc[4][2];
  layer_coop<2, false>(mT, abuf, wt_hi + WT_L0, wt_lo + WT_L0, bias + 0, acc, l, wq, wrow, wg, wrt, wslot);
  write_m(mT, acc, l, wq);
  __syncthreads();
  layer_coop<4, true>(mT, abuf, wt_hi + WT_L1, wt_lo + WT_L1, bias + 128, acc, l, wq, wrow, wg, wrt, wslot);
  write_m(mT, acc, l, wq);
  __syncthreads();
  layer_coop<4, true>(mT, abuf, wt_hi + WT_L2, wt_lo + WT_L2, bias + 256, acc, l, wq, wrow, wg, wrt, wslot);
  write_m(mT, acc, l, wq);
  __syncthreads();
  layer_coop<4, true>(mT, abuf, wt_hi + WT_L3, wt_lo + WT_L3, bias + 384, acc, l, wq, wrow, wg, wrt, wslot);
  write_m(mT, acc, l, wq);
  __syncthreads();

  // ---- L4: 128 -> 1 (wave wq: rows wq*16..+15; 4 lane-groups split p) ----
  {
    int r16 = l & 15, pq = l >> 4;
    int r = wq * 16 + r16;
    const float* w4h = w4 + pq * 32 * 9;
    float part = 0.0f;
#pragma unroll 4
    for (int pp = 0; pp < 32; ++pp) {
      float mm = mT[r * MST + pq * 32 + pp];
      const float* wp = w4h + pp * 9;
      part += wp[0];
      part = fmaf(mm, wp[1], part);
      float u2 = 1.0f, u1 = mm;
#pragma unroll
      for (int n = 2; n < 9; ++n) {
        float u = fmaf(mm, u1, -u2);
        u2 = u1;
        u1 = u;
        part = fmaf(u, wp[n], part);
      }
    }
    part += __shfl_xor(part, 16);
    part += __shfl_xor(part, 32);
    if (l < 16) {
      float v = part;
      float t = 0.5f * fast_tanh2(v);
      float m2 = t + t;
      float tm2 = 1.0f, tm1 = t;
      float y = gelu_exact(1.0f) + gelu_exact(t);
#pragma unroll
      for (int n = 2; n <= 5; ++n) {
        float tn = fmaf(m2, tm1, -tm2);
        tm2 = tm1;
        tm1 = tn;
        y += gelu_exact(tn);
      }
      out[row0 + r] = y;
    }
  }
}

extern "C" void kernel_launch(void* const* d_in, const int* in_sizes, int n_in,
                              void* d_out, int out_size, void* d_ws, size_t ws_size,
                              hipStream_t stream) {
  const float* x   = (const float*)d_in[0];
  const float* Bm  = (const float*)d_in[1];
  const float* W0  = (const float*)d_in[2];
  const float* tW0 = (const float*)d_in[3];
  const float* W1  = (const float*)d_in[4];
  const float* tW1 = (const float*)d_in[5];
  const float* W2  = (const float*)d_in[6];
  const float* tW2 = (const float*)d_in[7];
  const float* W3  = (const float*)d_in[8];
  const float* tW3 = (const float*)d_in[9];
  const float* W4  = (const float*)d_in[10];
  const float* tW4 = (const float*)d_in[11];

  _Float16* wt_hi = (_Float16*)d_ws;
  _Float16* wt_lo = wt_hi + WT_END;
  float* fws = (float*)d_ws + F32_BASE;
  float* bias = fws;        // 4*128 floats
  float* w4 = fws + 512;    // 1152 floats

  fuse_w_f16<<<65536 / 256, 256, 0, stream>>>(W0, tW0, wt_hi + WT_L0, wt_lo + WT_L0, 64, 65536, 1);
  fuse_w_f16<<<131072 / 256, 256, 0, stream>>>(W1, tW1, wt_hi + WT_L1, wt_lo + WT_L1, 128, 131072, 2);
  fuse_w_f16<<<131072 / 256, 256, 0, stream>>>(W2, tW2, wt_hi + WT_L2, wt_lo + WT_L2, 128, 131072, 2);
  fuse_w_f16<<<131072 / 256, 256, 0, stream>>>(W3, tW3, wt_hi + WT_L3, wt_lo + WT_L3, 128, 131072, 2);
  fuse_bias<<<2, 64, 0, stream>>>(W0, tW0, bias + 0, 64, 128);
  fuse_bias<<<2, 64, 0, stream>>>(W1, tW1, bias + 128, 128, 128);
  fuse_bias<<<2, 64, 0, stream>>>(W2, tW2, bias + 256, 128, 128);
  fuse_bias<<<2, 64, 0, stream>>>(W3, tW3, bias + 384, 128, 128);
  fuse_w4<<<9, 128, 0, stream>>>(W4, tW4, w4);

  kan_mfma<<<131072 / 64, TPB, 0, stream>>>(x, Bm, wt_hi, wt_lo, bias, w4, (float*)d_out);
}